// Round 1
// baseline (155.795 us; speedup 1.0000x reference)
//
#include <hip/hip_runtime.h>
#include <hip/hip_bf16.h>
#include <math.h>

#define BB 2
#define CC 192
#define LL 32
#define DI 384
#define SS 16
#define RR 12
#define KK 4

// ---------------- K1: one pass over x, all three axis-mean reductions ----------------
// grid = B*C blocks, block = 1024 threads. seq layout: seq[i][b][pos][c]
__global__ void k_reduce(const float* __restrict__ x, float* __restrict__ seq) {
  int bc = blockIdx.x; int b = bc / CC, c = bc % CC;
  const float* base = x + (size_t)bc * 32768;
  int t = threadIdx.x;
  int w = t & 31, r = t >> 5;   // r = d index
  float acc = 0.f;
  __shared__ float sH[32];
  __shared__ float sMat[1024];
  if (t < 32) sH[t] = 0.f;
  __syncthreads();
  for (int h = 0; h < 32; ++h) {
    float v = base[r * 1024 + h * 32 + w];
    acc += v;
    float vv = v;
    #pragma unroll
    for (int off = 32; off > 0; off >>= 1) vv += __shfl_down(vv, off, 64);
    if ((t & 63) == 0) atomicAdd(&sH[h], vv);
  }
  sMat[t] = acc;
  // seq0 (d): reduce acc over the 32 w-lanes sharing r
  float s0 = acc;
  #pragma unroll
  for (int off = 16; off > 0; off >>= 1) s0 += __shfl_down(s0, off, 32);
  if (w == 0) seq[((0 * BB + b) * 32 + r) * CC + c] = s0 * (1.f / 1024.f);
  __syncthreads();
  if (t < 32) {
    float s2 = 0.f;
    for (int rr = 0; rr < 32; ++rr) s2 += sMat[rr * 32 + t];
    seq[((2 * BB + b) * 32 + t) * CC + c] = s2 * (1.f / 1024.f);
    seq[((1 * BB + b) * 32 + t) * CC + c] = sH[t] * (1.f / 1024.f);
  }
}

// ---------------- K2: LayerNorm over C per token ----------------
// grid = 3*B*32, block = 192
__global__ void k_ln(const float* __restrict__ seq, const float* __restrict__ ln_w,
                     const float* __restrict__ ln_b, float* __restrict__ out) {
  int tok = blockIdx.x;
  int i = tok / (BB * 32);
  int c = threadIdx.x;
  float v = seq[tok * CC + c];
  float s = v, q = v * v;
  #pragma unroll
  for (int off = 32; off > 0; off >>= 1) { s += __shfl_down(s, off, 64); q += __shfl_down(q, off, 64); }
  __shared__ float sw[3], qw[3];
  int wid = c >> 6;
  if ((c & 63) == 0) { sw[wid] = s; qw[wid] = q; }
  __syncthreads();
  float S = sw[0] + sw[1] + sw[2], Q = qw[0] + qw[1] + qw[2];
  float mu = S / CC;
  float var = Q / CC - mu * mu;
  float xn = (v - mu) * rsqrtf(var + 1e-5f);
  out[tok * CC + c] = xn * ln_w[i * CC + c] + ln_b[i * CC + c];
}

// ---------------- K3: in-proj (token x 768, inner 192) ----------------
// grid = 3*B*32, block = 256
__global__ void k_inproj(const float* __restrict__ seqln, const float* __restrict__ in_w,
                         float* __restrict__ xmz) {
  int tok = blockIdx.x; int i = tok / (BB * 32);
  __shared__ float srow[CC];
  int t = threadIdx.x;
  if (t < CC) srow[t] = seqln[tok * CC + t];
  __syncthreads();
  const float* W = in_w + (size_t)i * 768 * CC;
  for (int j = t; j < 768; j += 256) {
    const float4* wr = (const float4*)(W + j * CC);
    const float4* sr = (const float4*)srow;
    float acc = 0.f;
    #pragma unroll 4
    for (int c4 = 0; c4 < CC / 4; ++c4) {
      float4 a = wr[c4], bq = sr[c4];
      acc += a.x * bq.x + a.y * bq.y + a.z * bq.z + a.w * bq.w;
    }
    xmz[tok * 768 + j] = acc;
  }
}

// ---------------- K4: causal conv K=4 + silu ----------------
// grid = 288, block = 256  (3*B*32*DI = 73728 threads)
__global__ void k_conv(const float* __restrict__ xmz, const float* __restrict__ conv_w,
                       const float* __restrict__ conv_b, float* __restrict__ xc) {
  int idx = blockIdx.x * 256 + threadIdx.x;
  if (idx >= 3 * BB * 32 * DI) return;
  int di = idx % DI; int tok = idx / DI; int l = tok & 31; int tb = tok >> 5; int i = tb / BB;
  const float* cw = conv_w + (i * DI + di) * KK;
  float acc = conv_b[i * DI + di];
  #pragma unroll
  for (int k = 0; k < KK; ++k) {
    int ls = l + k - 3;
    if (ls >= 0) acc += cw[k] * xmz[(tb * 32 + ls) * 768 + di];
  }
  acc = acc / (1.f + expf(-acc));   // silu
  xc[idx] = acc;
}

// ---------------- K5: xp-proj (44 outs) + dt-proj (384 outs) + softplus ----------------
// grid = 192 (tokens), block = 256
__global__ void k_xpdt(const float* __restrict__ xc, const float* __restrict__ xp_w,
                       const float* __restrict__ dt_w, const float* __restrict__ dt_b,
                       float* __restrict__ dbc, float* __restrict__ dt) {
  int tok = blockIdx.x; int tb = tok >> 5; int i = tb / BB;
  __shared__ float xrow[DI];
  __shared__ float dbcl[44];
  int t = threadIdx.x;
  for (int j = t; j < DI; j += 256) xrow[j] = xc[tok * DI + j];
  __syncthreads();
  if (t < 44) {
    const float* wr = xp_w + ((size_t)i * 44 + t) * DI;
    float acc = 0.f;
    for (int c2 = 0; c2 < DI; ++c2) acc += wr[c2] * xrow[c2];
    dbcl[t] = acc;
    dbc[tok * 44 + t] = acc;
  }
  __syncthreads();
  for (int di = t; di < DI; di += 256) {
    const float* wr = dt_w + ((size_t)i * DI + di) * RR;
    float acc = dt_b[i * DI + di];
    #pragma unroll
    for (int r = 0; r < RR; ++r) acc += wr[r] * dbcl[r];
    float sp = (acc > 20.f) ? acc : log1pf(expf(acc));
    dt[tok * DI + di] = sp;
  }
}

// ---------------- K6: selective scan; 16 lanes (s) per (i,b,di) group ----------------
// grid = 144, block = 256 (16 groups of 16)
__global__ void k_scan(const float* __restrict__ dbc, const float* __restrict__ dt,
                       const float* __restrict__ xc, const float* __restrict__ xmz,
                       const float* __restrict__ A_log, const float* __restrict__ Dskip,
                       float* __restrict__ y) {
  int gid = blockIdx.x * 16 + (threadIdx.x >> 4);
  int s = threadIdx.x & 15;
  if (gid >= 3 * BB * DI) return;
  int di = gid % DI; int ib = gid / DI;   // ib = i*B+b
  int i = ib / BB;
  float A = -expf(A_log[((size_t)i * DI + di) * SS + s]);
  float Dsk = Dskip[i * DI + di];
  float h = 0.f;
  int tokbase = ib * 32;
  for (int l = 0; l < 32; ++l) {
    int tok = tokbase + l;
    float dtt = dt[tok * DI + di];
    float xt = xc[tok * DI + di];
    float Bt = dbc[tok * 44 + RR + s];
    float Ct = dbc[tok * 44 + RR + SS + s];
    h = expf(dtt * A) * h + dtt * xt * Bt;
    float p = h * Ct;
    #pragma unroll
    for (int off = 8; off > 0; off >>= 1) p += __shfl_xor(p, off, 16);
    if (s == 0) {
      float z = xmz[tok * 768 + DI + di];
      float yv = (p + Dsk * xt) * (z / (1.f + expf(-z)));
      y[tok * DI + di] = yv;
    }
  }
}

// ---------------- K7: out-proj (C from DI) then up-proj (C from C) ----------------
// grid = 192 (tokens), block = 192
__global__ void k_outup(const float* __restrict__ y, const float* __restrict__ out_w,
                        const float* __restrict__ up_w, const float* __restrict__ up_b,
                        float* __restrict__ Z) {
  int tok = blockIdx.x; int tb = tok >> 5; int i = tb / BB;
  __shared__ float yrow[DI];
  __shared__ float mrow[CC];
  int t = threadIdx.x;
  yrow[t] = y[tok * DI + t];
  yrow[t + CC] = y[tok * DI + t + CC];
  __syncthreads();
  const float* wr = out_w + ((size_t)i * CC + t) * DI;
  float acc = 0.f;
  for (int d2 = 0; d2 < DI; ++d2) acc += wr[d2] * yrow[d2];
  mrow[t] = acc;
  __syncthreads();
  const float* ur = up_w + ((size_t)i * CC + t) * CC;
  float z = up_b[i * CC + t];
  for (int c2 = 0; c2 < CC; ++c2) z += ur[c2] * mrow[c2];
  Z[tok * CC + t] = z;
}

// ---------------- K8: gate context (means over pos + Wg matmul) ----------------
// grid = 6 (gate,b), block = 192
__global__ void k_ctx(const float* __restrict__ Z, const float* __restrict__ Wg_w,
                      const float* __restrict__ Wg_b, float* __restrict__ ctx) {
  int g = blockIdx.x / BB, b = blockIdx.x % BB;
  int o1, o2;
  if (g == 0) { o1 = 1; o2 = 2; } else if (g == 1) { o1 = 0; o2 = 2; } else { o1 = 0; o2 = 1; }
  __shared__ float gm[2][CC];
  int t = threadIdx.x;
  float s1 = 0.f, s2 = 0.f;
  for (int l = 0; l < 32; ++l) {
    s1 += Z[((o1 * BB + b) * 32 + l) * CC + t];
    s2 += Z[((o2 * BB + b) * 32 + l) * CC + t];
  }
  gm[0][t] = s1 * (1.f / 32.f);
  gm[1][t] = s2 * (1.f / 32.f);
  __syncthreads();
  const float* wr = Wg_w + t * 2 * CC;
  float acc = Wg_b[t];
  for (int c2 = 0; c2 < CC; ++c2) acc += wr[c2] * gm[0][c2] + wr[CC + c2] * gm[1][c2];
  ctx[(g * BB + b) * CC + t] = acc;
}

// ---------------- K9: gate apply: st -> relu -> Wm -> sigmoid -> Y -> P ----------------
// grid = 192 (g,b,l), block = 192
__global__ void k_gate(const float* __restrict__ Z, const float* __restrict__ ctx,
                       const float* __restrict__ Ws_w, const float* __restrict__ Ws_b,
                       const float* __restrict__ Wm_w, const float* __restrict__ Wm_b,
                       const float* __restrict__ po_w, float* __restrict__ P) {
  int blk = blockIdx.x;          // ((g*B+b)*32 + l)
  int gb = blk >> 5;             // g*B+b
  int g = gb / BB;
  int t = threadIdx.x;
  __shared__ float zrow[CC], arow[CC], yrow[CC];
  zrow[t] = Z[blk * CC + t];
  __syncthreads();
  const float* wr = Ws_w + t * CC;
  float st = Ws_b[t];
  for (int c2 = 0; c2 < CC; ++c2) st += wr[c2] * zrow[c2];
  float a = ctx[gb * CC + t] + st;
  arow[t] = a > 0.f ? a : 0.f;
  __syncthreads();
  const float* mr = Wm_w + t * CC;
  float am = Wm_b[t];
  for (int c2 = 0; c2 < CC; ++c2) am += mr[c2] * arow[c2];
  am = 1.f / (1.f + expf(-am));
  yrow[t] = am * zrow[t];
  __syncthreads();
  const float* pr = po_w + t * (3 * CC) + g * CC;
  float acc = 0.f;
  for (int c2 = 0; c2 < CC; ++c2) acc += pr[c2] * yrow[c2];
  P[blk * CC + t] = acc;
}

// ---------------- K10: instance-norm stats from separable P ----------------
// grid = 2, block = 192 (B*C threads)
__global__ void k_stats(const float* __restrict__ P, const float* __restrict__ po_b,
                        float* __restrict__ stats) {
  int idx = blockIdx.x * 192 + threadIdx.x;   // b*C + c
  int b = idx / CC, c = idx % CC;
  float mu = po_b[c];
  float var = 0.f;
  for (int g = 0; g < 3; ++g) {
    float s = 0.f, q = 0.f;
    for (int l = 0; l < 32; ++l) {
      float v = P[((g * BB + b) * 32 + l) * CC + c];
      s += v; q += v * v;
    }
    float m = s * (1.f / 32.f);
    mu += m;
    var += q * (1.f / 32.f) - m * m;
  }
  stats[idx * 2] = mu;
  stats[idx * 2 + 1] = rsqrtf(var + 1e-5f);
}

// ---------------- K11: final fused broadcast + residual ----------------
// grid = B*C, block = 256, float4
__global__ void k_final(const float* __restrict__ x, const float* __restrict__ P,
                        const float* __restrict__ stats, const float* __restrict__ po_b,
                        const float* __restrict__ rs_p, float* __restrict__ out) {
  int bc = blockIdx.x; int b = bc / CC, c = bc % CC;
  float rs = rs_p[0];
  __shared__ float p0[32], p1[32], p2[32];
  float mu = stats[bc * 2], istd = stats[bc * 2 + 1];
  float sc = rs * istd;
  int t = threadIdx.x;
  if (t < 32) {
    p0[t] = P[((0 * BB + b) * 32 + t) * CC + c] * sc;
    p1[t] = P[((1 * BB + b) * 32 + t) * CC + c] * sc;
    p2[t] = P[((2 * BB + b) * 32 + t) * CC + c] * sc;
  }
  __syncthreads();
  float basev = sc * (po_b[c] - mu);
  const float4* xin = (const float4*)(x + (size_t)bc * 32768);
  float4* xo = (float4*)(out + (size_t)bc * 32768);
  for (int q = t; q < 8192; q += 256) {
    int d = q >> 8, h = (q >> 3) & 31, w4 = (q & 7) * 4;
    float add = basev + p0[d] + p1[h];
    float4 v = xin[q];
    v.x += add + p2[w4];
    v.y += add + p2[w4 + 1];
    v.z += add + p2[w4 + 2];
    v.w += add + p2[w4 + 3];
    xo[q] = v;
  }
}

extern "C" void kernel_launch(void* const* d_in, const int* in_sizes, int n_in,
                              void* d_out, int out_size, void* d_ws, size_t ws_size,
                              hipStream_t stream) {
  const float* x      = (const float*)d_in[0];
  const float* ln_w   = (const float*)d_in[1];
  const float* ln_b   = (const float*)d_in[2];
  const float* in_w   = (const float*)d_in[3];
  const float* conv_w = (const float*)d_in[4];
  const float* conv_b = (const float*)d_in[5];
  const float* xp_w   = (const float*)d_in[6];
  const float* dt_w   = (const float*)d_in[7];
  const float* dt_b   = (const float*)d_in[8];
  const float* A_log  = (const float*)d_in[9];
  const float* Dskip  = (const float*)d_in[10];
  const float* out_w  = (const float*)d_in[11];
  const float* up_w   = (const float*)d_in[12];
  const float* up_b   = (const float*)d_in[13];
  const float* Wg_w   = (const float*)d_in[14];
  const float* Wg_b   = (const float*)d_in[15];
  const float* Ws_w   = (const float*)d_in[16];
  const float* Ws_b   = (const float*)d_in[17];
  const float* Wm_w   = (const float*)d_in[18];
  const float* Wm_b   = (const float*)d_in[19];
  const float* po_w   = (const float*)d_in[20];
  const float* po_b   = (const float*)d_in[21];
  const float* rs_p   = (const float*)d_in[22];
  float* out = (float*)d_out;

  float* ws    = (float*)d_ws;
  float* seq   = ws;               // 3*2*32*192 = 36864
  float* seqln = seq   + 36864;    // 36864
  float* xmz   = seqln + 36864;    // 3*2*32*768 = 147456
  float* xc    = xmz   + 147456;   // 3*2*32*384 = 73728
  float* dbc   = xc    + 73728;    // 192*44 = 8448
  float* dt    = dbc   + 8448;     // 73728
  float* y     = dt    + 73728;    // 73728
  float* Z     = y     + 73728;    // 36864
  float* ctx   = Z     + 36864;    // 3*2*192 = 1152
  float* P     = ctx   + 1152;     // 36864
  float* stats = P     + 36864;    // 768

  k_reduce<<<dim3(BB * CC), dim3(1024), 0, stream>>>(x, seq);
  k_ln<<<dim3(3 * BB * 32), dim3(CC), 0, stream>>>(seq, ln_w, ln_b, seqln);
  k_inproj<<<dim3(3 * BB * 32), dim3(256), 0, stream>>>(seqln, in_w, xmz);
  k_conv<<<dim3(288), dim3(256), 0, stream>>>(xmz, conv_w, conv_b, xc);
  k_xpdt<<<dim3(3 * BB * 32), dim3(256), 0, stream>>>(xc, xp_w, dt_w, dt_b, dbc, dt);
  k_scan<<<dim3(144), dim3(256), 0, stream>>>(dbc, dt, xc, xmz, A_log, Dskip, y);
  k_outup<<<dim3(3 * BB * 32), dim3(CC), 0, stream>>>(y, out_w, up_w, up_b, Z);
  k_ctx<<<dim3(6), dim3(CC), 0, stream>>>(Z, Wg_w, Wg_b, ctx);
  k_gate<<<dim3(3 * BB * 32), dim3(CC), 0, stream>>>(Z, ctx, Ws_w, Ws_b, Wm_w, Wm_b, po_w, P);
  k_stats<<<dim3(2), dim3(CC), 0, stream>>>(P, po_b, stats);
  k_final<<<dim3(BB * CC), dim3(256), 0, stream>>>(x, P, stats, po_b, rs_p, out);
}